// Round 20
// baseline (183.616 us; speedup 1.0000x reference)
//
#include <hip/hip_runtime.h>
#include <math.h>

#define Hh 128
#define Ww 128
#define HW (128*128)
#define PITCH 130
#define PADPX (130*130)

typedef unsigned short u16;
typedef unsigned int uint;
typedef _Float16 f16;
typedef __attribute__((ext_vector_type(8))) _Float16 f16x8;
typedef __attribute__((ext_vector_type(4))) float f32x4;

// ---------------- fused prep: cond->condp, edge zero (condp,hA,hB), x->xt2 ----------------
__global__ __launch_bounds__(256) void prep_all_k(
    const float* __restrict__ cond, const float* __restrict__ x,
    f16* __restrict__ condp, f16* __restrict__ hA, f16* __restrict__ hB,
    f16* __restrict__ xt2)
{
  int t = blockIdx.x * 256 + threadIdx.x;
  if (t < 32768) {                     // cond -> condp interior
    int b = t >> 14, p = t & 16383;
    int y = p >> 7, xx = p & 127;
    const float* cb = cond + (size_t)b * 133 * HW + p;
    f16* ob = condp + ((size_t)b * PADPX + (size_t)((y + 1) * PITCH + xx + 1)) * 160;
    for (int c = 0; c < 160; c += 8) {
      f16 buf[8];
      #pragma unroll
      for (int j = 0; j < 8; j++) {
        float v = (c + j < 133) ? cb[(size_t)(c + j) * HW] : 0.f;
        buf[j] = (f16)v;
      }
      *(uint4*)&ob[c] = *(uint4*)buf;
    }
    return;
  }
  t -= 32768;
  if (t < 20640) {                     // condp halo edges
    int b = t / 10320, i = t % 10320;
    int e = i / 20, q = i % 20;
    int y, xx;
    if (e < 130)      { y = 0;   xx = e; }
    else if (e < 260) { y = 129; xx = e - 130; }
    else { int j = e - 260; y = 1 + (j >> 1); xx = (j & 1) ? 129 : 0; }
    *(uint4*)&condp[((size_t)b * PADPX + (size_t)(y * PITCH + xx)) * 160 + q * 8] =
        make_uint4(0, 0, 0, 0);
    return;
  }
  t -= 20640;
  if (t < 16512) {                     // hA / hB halo edges
    f16* buf = (t < 8256) ? hA : hB;
    int i = t % 8256;
    int b = i / 4128; i %= 4128;
    int e = i / 8, q = i % 8;
    int y, xx;
    if (e < 130)      { y = 0;   xx = e; }
    else if (e < 260) { y = 129; xx = e - 130; }
    else { int j = e - 260; y = 1 + (j >> 1); xx = (j & 1) ? 129 : 0; }
    *(uint4*)&buf[((size_t)b * PADPX + (size_t)(y * PITCH + xx)) * 64 + q * 8] =
        make_uint4(0, 0, 0, 0);
    return;
  }
  t -= 16512;
  if (t < 524288) {                    // x -> xt2 paired layout
    int b = t / (16 * HW);
    int r = t % (16 * HW);
    int dg = r / HW, p = r % HW;
    int y = p >> 7, xx = p & 127;
    int x1 = min(xx + 1, 127);
    const float* xb = x + ((size_t)b * 64 + dg * 4) * HW + (size_t)y * Ww;
    f16 o[8];
    #pragma unroll
    for (int c = 0; c < 4; c++) {
      o[c] = (f16)xb[(size_t)c * HW + xx];
      o[4 + c] = (f16)xb[(size_t)c * HW + x1];
    }
    *(uint4*)&xt2[(size_t)t * 8] = *(uint4*)o;
  }
}

// ---------------- fused weight transposes ----------------
__global__ __launch_bounds__(256) void wtrans_all_k(
    const float* __restrict__ w1, const float* __restrict__ w2,
    const float* __restrict__ w3, const float* __restrict__ w4,
    const float* __restrict__ wD,
    f16* __restrict__ wt1, f16* __restrict__ wt2, f16* __restrict__ wt3,
    f16* __restrict__ wt4, f16* __restrict__ wtd)
{
  int idx = blockIdx.x * 256 + threadIdx.x;
  if (idx >= 882 * 64) return;
  int lane = idx & 63;
  int fid = idx >> 6;
  if (fid >= 810) {                    // dcn: 72 frags, K=576 (ci = k*64 + dg*4 + c)
    int f2 = fid - 810;
    int f = f2 & 3, chunk = f2 >> 2;
    int co = f * 16 + (lane & 15);
    int ci0 = chunk * 32 + (lane >> 4) * 8;
    f16 buf[8];
    #pragma unroll
    for (int j = 0; j < 8; j++) {
      int ci = ci0 + j;
      buf[j] = (f16)wD[((size_t)co * 64 + (ci & 63)) * 9 + (ci >> 6)];
    }
    *(uint4*)&wtd[((size_t)f2 * 64 + lane) * 8] = *(uint4*)buf;
    return;
  }
  const float* w; f16* wt; int CIN, NC, NCOF;
  if (fid < 180)      { w = w1; wt = wt1; CIN = 133; NC = 5; NCOF = 4; }
  else if (fid < 252) { w = w2; wt = wt2; CIN = 64; NC = 2; NCOF = 4; fid -= 180; }
  else if (fid < 324) { w = w3; wt = wt3; CIN = 64; NC = 2; NCOF = 4; fid -= 252; }
  else                { w = w4; wt = wt4; CIN = 64; NC = 2; NCOF = 27; fid -= 324; }
  int f = fid % NCOF;
  int rest = fid / NCOF;
  int c = rest % NC;
  int tt = rest / NC;
  int co = f * 16 + (lane & 15);
  int ci0 = c * 32 + (lane >> 4) * 8;
  f16 buf[8];
  #pragma unroll
  for (int j = 0; j < 8; j++) {
    int ci = ci0 + j;
    buf[j] = (f16)((ci < CIN) ? w[((size_t)co * CIN + ci) * 9 + tt] : 0.f);
  }
  *(uint4*)&wt[((size_t)fid * 64 + lane) * 8] = *(uint4*)buf;
}

// ---------------- conv1-3: f16 MFMA, 16x8 tile, NCSTG staging (proven config) -------------
template<int CINP, int NC, int NCSTG, int NCF, int NCOF>
__global__ __launch_bounds__(256) void conv_f16_k(
    const f16* __restrict__ in, const f16* __restrict__ wt,
    const float* __restrict__ bias, f16* __restrict__ out, int cogroups)
{
  __shared__ u16 lds[NCSTG * 180 * 40];
  const int tid = threadIdx.x;
  const int lane = tid & 63, wave = tid >> 6;
  const int b = blockIdx.z / cogroups, cog = blockIdx.z % cogroups;
  const int gx0 = blockIdx.x * 16, gy0 = blockIdx.y * 8;

  f32x4 acc[2][NCF];
  #pragma unroll
  for (int i = 0; i < 2; i++)
    #pragma unroll
    for (int j = 0; j < NCF; j++) acc[i][j] = (f32x4)0.f;

  const f16* inb = in + (size_t)b * PADPX * CINP;

  for (int c0 = 0; c0 < NC; c0 += NCSTG) {
    const int nch = (NC - c0 < NCSTG) ? (NC - c0) : NCSTG;
    __syncthreads();
    for (int i = tid; i < nch * 720; i += 256) {
      int cc = i / 720, r = i - cc * 720;
      int pidx = r >> 2, q = r & 3;
      int py = pidx / 18, px = pidx - py * 18;
      size_t gp = (size_t)((gy0 + py) * PITCH + gx0 + px);
      uint4 v = *(const uint4*)&inb[gp * CINP + (c0 + cc) * 32 + q * 8];
      *(uint4*)&lds[cc * 7200 + pidx * 40 + ((q ^ ((pidx >> 3) & 3)) * 8)] = v;
    }
    __syncthreads();

    for (int cl = 0; cl < NCSTG; cl++) {
      if (c0 + cl >= NC) break;
      const int c = c0 + cl;
      #pragma unroll
      for (int tap = 0; tap < 9; tap++) {
        const int dy = tap / 3, dx = tap % 3;
        f16x8 bfrag[2];
        #pragma unroll
        for (int pl = 0; pl < 2; pl++) {
          int pr = (wave * 2 + pl + dy) * 18 + (lane & 15) + dx;
          bfrag[pl] = *(const f16x8*)&lds[cl * 7200 + pr * 40
                        + ((((lane >> 4)) ^ ((pr >> 3) & 3)) * 8)];
        }
        const f16* fA = wt + (((size_t)(tap * NC + c)) * NCOF + cog * NCF) * 512
                        + (size_t)lane * 8;
        #pragma unroll
        for (int cf = 0; cf < NCF; cf++) {
          f16x8 a = *(const f16x8*)&fA[(size_t)cf * 512];
          #pragma unroll
          for (int pl = 0; pl < 2; pl++)
            acc[pl][cf] = __builtin_amdgcn_mfma_f32_16x16x32_f16(a, bfrag[pl], acc[pl][cf], 0, 0, 0);
        }
      }
    }
  }

  const int co_l = (lane >> 4) * 4;
  #pragma unroll
  for (int pl = 0; pl < 2; pl++) {
    size_t pp = (size_t)((gy0 + wave * 2 + pl + 1) * PITCH + gx0 + (lane & 15) + 1);
    f16* ob = out + ((size_t)b * PADPX + pp) * (NCOF * 16);
    #pragma unroll
    for (int cf = 0; cf < NCF; cf++) {
      int c0 = (cog * NCF + cf) * 16 + co_l;
      f16 buf[4];
      #pragma unroll
      for (int r = 0; r < 4; r++) {
        float v = acc[pl][cf][r] + bias[c0 + r];
        buf[r] = (f16)((v >= 0.f) ? v : 0.1f * v);
      }
      *(uint2*)&ob[c0] = *(uint2*)buf;
    }
  }
}

// ---------------- conv4: direct-from-global f16 MFMA, no LDS, no barriers -----------------
// grid (8,16,B*27), 256 thr. Per chunk: hoist 12 B-frags (4 rows x 3 dx) from global
// NHWC (row-base addr + immediate offsets), then 9-tap x 2-MFMA static loop.
__global__ __launch_bounds__(256) void conv4_direct_k(
    const f16* __restrict__ in, const f16* __restrict__ wt,
    const float* __restrict__ bias, f16* __restrict__ offb, f16* __restrict__ mskb,
    const float* __restrict__ flow)
{
  const int tid = threadIdx.x;
  const int lane = tid & 63, wave = tid >> 6;
  const int b = blockIdx.z / 27, cog = blockIdx.z % 27;
  const int gx0 = blockIdx.x * 16, gy0 = blockIdx.y * 8;

  f32x4 acc[2];
  acc[0] = (f32x4)0.f; acc[1] = (f32x4)0.f;

  // row base pointers (4 rows this wave touches), 16B-granule per lane
  const f16* inb = in + (size_t)b * PADPX * 64
                   + (size_t)(gx0 + (lane & 15)) * 64 + (lane >> 4) * 8;

  #pragma unroll
  for (int c = 0; c < 2; c++) {
    f16x8 breg[4][3];
    #pragma unroll
    for (int rr = 0; rr < 4; rr++) {
      const f16* rp = inb + (size_t)((gy0 + wave * 2 + rr) * PITCH) * 64 + c * 32;
      breg[rr][0] = *(const f16x8*)&rp[0];
      breg[rr][1] = *(const f16x8*)&rp[64];
      breg[rr][2] = *(const f16x8*)&rp[128];
    }
    #pragma unroll
    for (int tap = 0; tap < 9; tap++) {
      const int dy = tap / 3, dx = tap % 3;
      f16x8 a = *(const f16x8*)&wt[(((size_t)(tap * 2 + c)) * 27 + cog) * 512
                                   + (size_t)lane * 8];
      acc[0] = __builtin_amdgcn_mfma_f32_16x16x32_f16(a, breg[0 + dy][dx], acc[0], 0, 0, 0);
      acc[1] = __builtin_amdgcn_mfma_f32_16x16x32_f16(a, breg[1 + dy][dx], acc[1], 0, 0, 0);
    }
  }

  const int co_l = (lane >> 4) * 4;
  #pragma unroll
  for (int pl = 0; pl < 2; pl++) {
    size_t pix = (size_t)(gy0 + wave * 2 + pl) * Ww + gx0 + (lane & 15);
    float fl0 = flow[((size_t)b * 2 + 0) * HW + pix];
    float fl1 = flow[((size_t)b * 2 + 1) * HW + pix];
    int c0 = cog * 16 + co_l;
    #pragma unroll
    for (int r = 0; r < 4; r++) {
      int cc = c0 + r;
      float v = acc[pl][r] + bias[cc];
      if (cc < 288) {
        float e = __expf(2.f * v);
        float t = 1.f - 2.f * __builtin_amdgcn_rcpf(e + 1.f);
        offb[((size_t)b * 288 + cc) * HW + pix] =
            (f16)(10.f * t + ((cc & 1) ? fl0 : fl1));
      } else {
        mskb[((size_t)b * 144 + (cc - 288)) * HW + pix] =
            (f16)__builtin_amdgcn_rcpf(1.f + __expf(-v));
      }
    }
  }
}

// ---------------- fused dcn: R8 structure (64 px/block, LDS double-buffered), f16 offsets --
__global__ __launch_bounds__(256) void dcn_fused_k(
    const f16* __restrict__ xt2, const f16* __restrict__ off,
    const f16* __restrict__ msk, const f16* __restrict__ wtd,
    const float* __restrict__ bias, float* __restrict__ out)
{
  __shared__ u16 buf[2][64][72];
  const int tid = threadIdx.x;
  const int lane = tid & 63, wave = tid >> 6;
  const int bid = blockIdx.x;
  const int nid = (bid & 7) * 64 + (bid >> 3);   // XCD-contiguous remap (512 = 8*64)
  const int b = nid >> 8;
  const int px0 = (nid & 255) * 64;
  const int pxl = tid & 63;
  const int px = px0 + pxl;
  const int y = px >> 7, x0i = px & 127;
  const int dg2 = tid >> 6;

  const f16* offp = off + (size_t)b * 288 * HW + px;
  const f16* mp   = msk + (size_t)b * 144 * HW + px;
  const f16* xpl  = xt2 + (size_t)(b * 16 + dg2 * 4) * ((size_t)HW * 8);

  f32x4 acc[4];
  #pragma unroll
  for (int f = 0; f < 4; f++) acc[f] = (f32x4)0.f;

  float dyv[2][4], dxv[2][4], mvv[2][4];
  f16x8 g0[4], g1[4];
  float w00[4], w01[4], w10[4], w11[4];
  int hsel[4];

#define OFF_LOAD(kk, sl) { \
  _Pragma("unroll") \
  for (int i = 0; i < 4; i++) { int dg = dg2 * 4 + i; \
    dyv[sl][i] = (float)offp[(size_t)(dg * 18 + 2 * (kk)) * HW]; \
    dxv[sl][i] = (float)offp[(size_t)(dg * 18 + 2 * (kk) + 1) * HW]; \
    mvv[sl][i] = (float)mp[(size_t)(dg * 9 + (kk)) * HW]; } }

#define GATHER(kk, sl) { \
  _Pragma("unroll") \
  for (int i = 0; i < 4; i++) { \
    float py = (float)(y - 1 + (kk) / 3) + dyv[sl][i]; \
    float pxx = (float)(x0i - 1 + (kk) % 3) + dxv[sl][i]; \
    float y0f = floorf(py), x0f = floorf(pxx); \
    float wy = py - y0f, wx = pxx - x0f; \
    int yi = (int)y0f, xi = (int)x0f; \
    bool vy0 = (yi >= 0) & (yi < Hh); \
    bool vy1 = (yi + 1 >= 0) & (yi + 1 < Hh); \
    bool vx0 = (xi >= 0) & (xi < Ww); \
    bool vx1 = (xi + 1 >= 0) & (xi + 1 < Ww); \
    int y0c = min(max(yi, 0), Hh - 1), y1c = min(max(yi + 1, 0), Hh - 1); \
    int xb = min(max(xi, 0), Ww - 1); \
    hsel[i] = min(max(xi + 1, 0), Ww - 1) - xb; \
    float mv = mvv[sl][i]; \
    w00[i] = (vy0 && vx0) ? (1.f - wy) * (1.f - wx) * mv : 0.f; \
    w01[i] = (vy0 && vx1) ? (1.f - wy) * wx * mv : 0.f; \
    w10[i] = (vy1 && vx0) ? wy * (1.f - wx) * mv : 0.f; \
    w11[i] = (vy1 && vx1) ? wy * wx * mv : 0.f; \
    const f16* xp = xpl + (size_t)i * ((size_t)HW * 8); \
    g0[i] = *(const f16x8*)&xp[(size_t)(y0c * Ww + xb) * 8]; \
    g1[i] = *(const f16x8*)&xp[(size_t)(y1c * Ww + xb) * 8]; } }

#define FIN(nb) { \
  f16 o[16]; \
  _Pragma("unroll") \
  for (int i = 0; i < 4; i++) { \
    _Pragma("unroll") \
    for (int c = 0; c < 4; c++) { \
      float a00 = (float)g0[i][c]; \
      float a01 = hsel[i] ? (float)g0[i][4 + c] : (float)g0[i][c]; \
      float a10 = (float)g1[i][c]; \
      float a11 = hsel[i] ? (float)g1[i][4 + c] : (float)g1[i][c]; \
      o[i * 4 + c] = (f16)(a00 * w00[i] + a01 * w01[i] + a10 * w10[i] + a11 * w11[i]); } } \
  *(uint4*)&buf[nb][pxl][dg2 * 16] = *(uint4*)&o[0]; \
  *(uint4*)&buf[nb][pxl][dg2 * 16 + 8] = *(uint4*)&o[8]; }

#define MFMA_TAP(kk) { \
  _Pragma("unroll") \
  for (int ch = 0; ch < 2; ch++) { \
    f16x8 bfr = *(const f16x8*)&buf[(kk) & 1][wave * 16 + (lane & 15)][(lane >> 4) * 8 + ch * 32]; \
    const f16* wc = wtd + ((size_t)(((kk) * 2 + ch) * 4) * 64 + (size_t)lane) * 8; \
    _Pragma("unroll") \
    for (int f = 0; f < 4; f++) { \
      f16x8 a = *(const f16x8*)&wc[(size_t)f * 512]; \
      acc[f] = __builtin_amdgcn_mfma_f32_16x16x32_f16(a, bfr, acc[f], 0, 0, 0); } } }

  OFF_LOAD(0, 0);
  GATHER(0, 0);
  OFF_LOAD(1, 1);
  FIN(0);
  __syncthreads();

  #pragma unroll
  for (int k = 0; k < 9; k++) {
    if (k < 8) { GATHER(k + 1, (k + 1) & 1); }
    if (k < 7) { OFF_LOAD(k + 2, k & 1); }
    MFMA_TAP(k);
    if (k < 8) { FIN((k + 1) & 1); }
    __syncthreads();
  }

  const int pxo = px0 + wave * 16 + (lane & 15);
  #pragma unroll
  for (int f = 0; f < 4; f++) {
    #pragma unroll
    for (int r = 0; r < 4; r++) {
      int co = f * 16 + (lane >> 4) * 4 + r;
      out[((size_t)b * 64 + co) * HW + pxo] = acc[f][r] + bias[co];
    }
  }
#undef OFF_LOAD
#undef GATHER
#undef FIN
#undef MFMA_TAP
}

// ---------------- launch ----------------
extern "C" void kernel_launch(void* const* d_in, const int* in_sizes, int n_in,
                              void* d_out, int out_size, void* d_ws, size_t ws_size,
                              hipStream_t stream) {
  const float* x    = (const float*)d_in[0];
  const float* cond = (const float*)d_in[1];
  const float* flow = (const float*)d_in[2];
  const float* w1 = (const float*)d_in[3];
  const float* b1 = (const float*)d_in[4];
  const float* w2 = (const float*)d_in[5];
  const float* b2 = (const float*)d_in[6];
  const float* w3 = (const float*)d_in[7];
  const float* b3 = (const float*)d_in[8];
  const float* w4 = (const float*)d_in[9];
  const float* b4 = (const float*)d_in[10];
  const float* wD = (const float*)d_in[11];
  const float* bD = (const float*)d_in[12];
  float* out = (float*)d_out;
  const int B = 2;

  char* ws = (char*)d_ws;
  f16* condp = (f16*)ws;                         // 10,816,000
  f16* hA = (f16*)(ws + 10816000);               //  4,326,400
  f16* hB = (f16*)(ws + 15142400);               //  4,326,400
  char* pw = ws + 19468800;
  f16*   offb = (f16*)pw;            pw += 18874368;  // [B][288][HW] f16
  f16*   mskb = (f16*)pw;            pw += 9437184;   // [B][144][HW] f16
  f16*   xt2  = (f16*)pw;            pw += 8388608;
  f16*   wt1  = (f16*)pw;            pw += 184320;
  f16*   wt2  = (f16*)pw;            pw += 73728;
  f16*   wt3  = (f16*)pw;            pw += 73728;
  f16*   wt4  = (f16*)pw;            pw += 497664;
  f16*   wtd  = (f16*)pw;            pw += 73728;

  // fused prep + fused weight transposes (2 launches)
  prep_all_k<<<dim3((594208 + 255) / 256), 256, 0, stream>>>(cond, x, condp, hA, hB, xt2);
  wtrans_all_k<<<dim3((882 * 64 + 255) / 256), 256, 0, stream>>>(
      w1, w2, w3, w4, wD, wt1, wt2, wt3, wt4, wtd);

  // conv1-3 (LDS-staged, proven) ; conv4 direct-from-global (no LDS, no barriers)
  conv_f16_k<160, 5, 2, 1, 4><<<dim3(8, 16, B * 4), 256, 0, stream>>>(
      condp, wt1, b1, hA, 4);
  conv_f16_k<64, 2, 2, 1, 4><<<dim3(8, 16, B * 4), 256, 0, stream>>>(
      hA, wt2, b2, hB, 4);
  conv_f16_k<64, 2, 2, 1, 4><<<dim3(8, 16, B * 4), 256, 0, stream>>>(
      hB, wt3, b3, hA, 4);
  conv4_direct_k<<<dim3(8, 16, B * 27), 256, 0, stream>>>(
      hA, wt4, b4, offb, mskb, flow);

  // fused deformable conv: R8 structure, f16 offsets
  dcn_fused_k<<<dim3(512), 256, 0, stream>>>(xt2, offb, mskb, wtd, bD, out);
}

// Round 21
// 122.453 us; speedup vs baseline: 1.4995x; 1.4995x over previous
//
#include <hip/hip_runtime.h>
#include <math.h>

#define Hh 128
#define Ww 128
#define HW (128*128)
#define PITCH 130
#define PADPX (130*130)

typedef unsigned short u16;
typedef unsigned int uint;
typedef _Float16 f16;
typedef __attribute__((ext_vector_type(8))) _Float16 f16x8;
typedef __attribute__((ext_vector_type(4))) float f32x4;

// ---------------- fused prep: cond->condp, edge zero (condp,hA,hB), x->xt2 ----------------
__global__ __launch_bounds__(256) void prep_all_k(
    const float* __restrict__ cond, const float* __restrict__ x,
    f16* __restrict__ condp, f16* __restrict__ hA, f16* __restrict__ hB,
    f16* __restrict__ xt2)
{
  int t = blockIdx.x * 256 + threadIdx.x;
  if (t < 32768) {                     // cond -> condp interior
    int b = t >> 14, p = t & 16383;
    int y = p >> 7, xx = p & 127;
    const float* cb = cond + (size_t)b * 133 * HW + p;
    f16* ob = condp + ((size_t)b * PADPX + (size_t)((y + 1) * PITCH + xx + 1)) * 160;
    for (int c = 0; c < 160; c += 8) {
      f16 buf[8];
      #pragma unroll
      for (int j = 0; j < 8; j++) {
        float v = (c + j < 133) ? cb[(size_t)(c + j) * HW] : 0.f;
        buf[j] = (f16)v;
      }
      *(uint4*)&ob[c] = *(uint4*)buf;
    }
    return;
  }
  t -= 32768;
  if (t < 20640) {                     // condp halo edges
    int b = t / 10320, i = t % 10320;
    int e = i / 20, q = i % 20;
    int y, xx;
    if (e < 130)      { y = 0;   xx = e; }
    else if (e < 260) { y = 129; xx = e - 130; }
    else { int j = e - 260; y = 1 + (j >> 1); xx = (j & 1) ? 129 : 0; }
    *(uint4*)&condp[((size_t)b * PADPX + (size_t)(y * PITCH + xx)) * 160 + q * 8] =
        make_uint4(0, 0, 0, 0);
    return;
  }
  t -= 20640;
  if (t < 16512) {                     // hA / hB halo edges
    f16* buf = (t < 8256) ? hA : hB;
    int i = t % 8256;
    int b = i / 4128; i %= 4128;
    int e = i / 8, q = i % 8;
    int y, xx;
    if (e < 130)      { y = 0;   xx = e; }
    else if (e < 260) { y = 129; xx = e - 130; }
    else { int j = e - 260; y = 1 + (j >> 1); xx = (j & 1) ? 129 : 0; }
    *(uint4*)&buf[((size_t)b * PADPX + (size_t)(y * PITCH + xx)) * 64 + q * 8] =
        make_uint4(0, 0, 0, 0);
    return;
  }
  t -= 16512;
  if (t < 524288) {                    // x -> xt2 paired layout
    int b = t / (16 * HW);
    int r = t % (16 * HW);
    int dg = r / HW, p = r % HW;
    int y = p >> 7, xx = p & 127;
    int x1 = min(xx + 1, 127);
    const float* xb = x + ((size_t)b * 64 + dg * 4) * HW + (size_t)y * Ww;
    f16 o[8];
    #pragma unroll
    for (int c = 0; c < 4; c++) {
      o[c] = (f16)xb[(size_t)c * HW + xx];
      o[4 + c] = (f16)xb[(size_t)c * HW + x1];
    }
    *(uint4*)&xt2[(size_t)t * 8] = *(uint4*)o;
  }
}

// ---------------- fused weight transposes ----------------
__global__ __launch_bounds__(256) void wtrans_all_k(
    const float* __restrict__ w1, const float* __restrict__ w2,
    const float* __restrict__ w3, const float* __restrict__ w4,
    const float* __restrict__ wD,
    f16* __restrict__ wt1, f16* __restrict__ wt2, f16* __restrict__ wt3,
    f16* __restrict__ wt4, f16* __restrict__ wtd)
{
  int idx = blockIdx.x * 256 + threadIdx.x;
  if (idx >= 882 * 64) return;
  int lane = idx & 63;
  int fid = idx >> 6;
  if (fid >= 810) {                    // dcn: 72 frags, K=576 (ci = k*64 + dg*4 + c)
    int f2 = fid - 810;
    int f = f2 & 3, chunk = f2 >> 2;
    int co = f * 16 + (lane & 15);
    int ci0 = chunk * 32 + (lane >> 4) * 8;
    f16 buf[8];
    #pragma unroll
    for (int j = 0; j < 8; j++) {
      int ci = ci0 + j;
      buf[j] = (f16)wD[((size_t)co * 64 + (ci & 63)) * 9 + (ci >> 6)];
    }
    *(uint4*)&wtd[((size_t)f2 * 64 + lane) * 8] = *(uint4*)buf;
    return;
  }
  const float* w; f16* wt; int CIN, NC, NCOF;
  if (fid < 180)      { w = w1; wt = wt1; CIN = 133; NC = 5; NCOF = 4; }
  else if (fid < 252) { w = w2; wt = wt2; CIN = 64; NC = 2; NCOF = 4; fid -= 180; }
  else if (fid < 324) { w = w3; wt = wt3; CIN = 64; NC = 2; NCOF = 4; fid -= 252; }
  else                { w = w4; wt = wt4; CIN = 64; NC = 2; NCOF = 27; fid -= 324; }
  int f = fid % NCOF;
  int rest = fid / NCOF;
  int c = rest % NC;
  int tt = rest / NC;
  int co = f * 16 + (lane & 15);
  int ci0 = c * 32 + (lane >> 4) * 8;
  f16 buf[8];
  #pragma unroll
  for (int j = 0; j < 8; j++) {
    int ci = ci0 + j;
    buf[j] = (f16)((ci < CIN) ? w[((size_t)co * CIN + ci) * 9 + tt] : 0.f);
  }
  *(uint4*)&wt[((size_t)fid * 64 + lane) * 8] = *(uint4*)buf;
}

// ---------------- conv3x3 via f16 MFMA, 16x8 tile, NCSTG staging, hoisted B-frags ---------
template<int CINP, int NC, int NCSTG, int NCF, int NCOF, int EPI>
__global__ __launch_bounds__(256) void conv_f16_k(
    const f16* __restrict__ in, const f16* __restrict__ wt,
    const float* __restrict__ bias, f16* __restrict__ out,
    f16* __restrict__ offb, f16* __restrict__ mskb,
    const float* __restrict__ flow, int cogroups)
{
  __shared__ u16 lds[NCSTG * 180 * 40];
  const int tid = threadIdx.x;
  const int lane = tid & 63, wave = tid >> 6;
  const int b = blockIdx.z / cogroups, cog = blockIdx.z % cogroups;
  const int gx0 = blockIdx.x * 16, gy0 = blockIdx.y * 8;

  f32x4 acc[2][NCF];
  #pragma unroll
  for (int i = 0; i < 2; i++)
    #pragma unroll
    for (int j = 0; j < NCF; j++) acc[i][j] = (f32x4)0.f;

  const f16* inb = in + (size_t)b * PADPX * CINP;

  for (int c0 = 0; c0 < NC; c0 += NCSTG) {
    const int nch = (NC - c0 < NCSTG) ? (NC - c0) : NCSTG;
    __syncthreads();
    for (int i = tid; i < nch * 720; i += 256) {
      int cc = i / 720, r = i - cc * 720;
      int pidx = r >> 2, q = r & 3;
      int py = pidx / 18, px = pidx - py * 18;
      size_t gp = (size_t)((gy0 + py) * PITCH + gx0 + px);
      uint4 v = *(const uint4*)&inb[gp * CINP + (c0 + cc) * 32 + q * 8];
      *(uint4*)&lds[cc * 7200 + pidx * 40 + ((q ^ ((pidx >> 3) & 3)) * 8)] = v;
    }
    __syncthreads();

    for (int cl = 0; cl < NCSTG; cl++) {
      if (c0 + cl >= NC) break;
      const int c = c0 + cl;
      // hoist 12 distinct B-fragments into registers
      f16x8 breg[4][3];
      #pragma unroll
      for (int rr = 0; rr < 4; rr++) {
        #pragma unroll
        for (int dxx = 0; dxx < 3; dxx++) {
          int pr = (wave * 2 + rr) * 18 + (lane & 15) + dxx;
          breg[rr][dxx] = *(const f16x8*)&lds[cl * 7200 + pr * 40
                          + ((((lane >> 4)) ^ ((pr >> 3) & 3)) * 8)];
        }
      }
      #pragma unroll
      for (int tap = 0; tap < 9; tap++) {
        const int dy = tap / 3, dx = tap % 3;
        const f16* fA = wt + (((size_t)(tap * NC + c)) * NCOF + cog * NCF) * 512
                        + (size_t)lane * 8;
        #pragma unroll
        for (int cf = 0; cf < NCF; cf++) {
          f16x8 a = *(const f16x8*)&fA[(size_t)cf * 512];
          acc[0][cf] = __builtin_amdgcn_mfma_f32_16x16x32_f16(a, breg[0 + dy][dx], acc[0][cf], 0, 0, 0);
          acc[1][cf] = __builtin_amdgcn_mfma_f32_16x16x32_f16(a, breg[1 + dy][dx], acc[1][cf], 0, 0, 0);
        }
      }
    }
  }

  const int co_l = (lane >> 4) * 4;
  if (EPI == 0) {
    #pragma unroll
    for (int pl = 0; pl < 2; pl++) {
      size_t pp = (size_t)((gy0 + wave * 2 + pl + 1) * PITCH + gx0 + (lane & 15) + 1);
      f16* ob = out + ((size_t)b * PADPX + pp) * (NCOF * 16);
      #pragma unroll
      for (int cf = 0; cf < NCF; cf++) {
        int c0 = (cog * NCF + cf) * 16 + co_l;
        f16 buf[4];
        #pragma unroll
        for (int r = 0; r < 4; r++) {
          float v = acc[pl][cf][r] + bias[c0 + r];
          buf[r] = (f16)((v >= 0.f) ? v : 0.1f * v);
        }
        *(uint2*)&ob[c0] = *(uint2*)buf;
      }
    }
  } else {
    #pragma unroll
    for (int pl = 0; pl < 2; pl++) {
      size_t pix = (size_t)(gy0 + wave * 2 + pl) * Ww + gx0 + (lane & 15);
      float fl0 = flow[((size_t)b * 2 + 0) * HW + pix];
      float fl1 = flow[((size_t)b * 2 + 1) * HW + pix];
      #pragma unroll
      for (int cf = 0; cf < NCF; cf++) {
        int c0 = (cog * NCF + cf) * 16 + co_l;
        #pragma unroll
        for (int r = 0; r < 4; r++) {
          int cc = c0 + r;
          float v = acc[pl][cf][r] + bias[cc];
          if (cc < 288) {
            float e = __expf(2.f * v);
            float t = 1.f - 2.f * __builtin_amdgcn_rcpf(e + 1.f);
            offb[((size_t)b * 288 + cc) * HW + pix] =
                (f16)(10.f * t + ((cc & 1) ? fl0 : fl1));
          } else {
            mskb[((size_t)b * 144 + (cc - 288)) * HW + pix] =
                (f16)__builtin_amdgcn_rcpf(1.f + __expf(-v));
          }
        }
      }
    }
  }
}

// ---------------- fused dcn: R8 structure (64 px/block, LDS double-buffered), f16 offsets --
__global__ __launch_bounds__(256) void dcn_fused_k(
    const f16* __restrict__ xt2, const f16* __restrict__ off,
    const f16* __restrict__ msk, const f16* __restrict__ wtd,
    const float* __restrict__ bias, float* __restrict__ out)
{
  __shared__ u16 buf[2][64][72];
  const int tid = threadIdx.x;
  const int lane = tid & 63, wave = tid >> 6;
  const int bid = blockIdx.x;
  const int nid = (bid & 7) * 64 + (bid >> 3);   // XCD-contiguous remap (512 = 8*64)
  const int b = nid >> 8;
  const int px0 = (nid & 255) * 64;
  const int pxl = tid & 63;
  const int px = px0 + pxl;
  const int y = px >> 7, x0i = px & 127;
  const int dg2 = tid >> 6;

  const f16* offp = off + (size_t)b * 288 * HW + px;
  const f16* mp   = msk + (size_t)b * 144 * HW + px;
  const f16* xpl  = xt2 + (size_t)(b * 16 + dg2 * 4) * ((size_t)HW * 8);

  f32x4 acc[4];
  #pragma unroll
  for (int f = 0; f < 4; f++) acc[f] = (f32x4)0.f;

  float dyv[2][4], dxv[2][4], mvv[2][4];
  f16x8 g0[4], g1[4];
  float w00[4], w01[4], w10[4], w11[4];
  int hsel[4];

#define OFF_LOAD(kk, sl) { \
  _Pragma("unroll") \
  for (int i = 0; i < 4; i++) { int dg = dg2 * 4 + i; \
    dyv[sl][i] = (float)offp[(size_t)(dg * 18 + 2 * (kk)) * HW]; \
    dxv[sl][i] = (float)offp[(size_t)(dg * 18 + 2 * (kk) + 1) * HW]; \
    mvv[sl][i] = (float)mp[(size_t)(dg * 9 + (kk)) * HW]; } }

#define GATHER(kk, sl) { \
  _Pragma("unroll") \
  for (int i = 0; i < 4; i++) { \
    float py = (float)(y - 1 + (kk) / 3) + dyv[sl][i]; \
    float pxx = (float)(x0i - 1 + (kk) % 3) + dxv[sl][i]; \
    float y0f = floorf(py), x0f = floorf(pxx); \
    float wy = py - y0f, wx = pxx - x0f; \
    int yi = (int)y0f, xi = (int)x0f; \
    bool vy0 = (yi >= 0) & (yi < Hh); \
    bool vy1 = (yi + 1 >= 0) & (yi + 1 < Hh); \
    bool vx0 = (xi >= 0) & (xi < Ww); \
    bool vx1 = (xi + 1 >= 0) & (xi + 1 < Ww); \
    int y0c = min(max(yi, 0), Hh - 1), y1c = min(max(yi + 1, 0), Hh - 1); \
    int xb = min(max(xi, 0), Ww - 1); \
    hsel[i] = min(max(xi + 1, 0), Ww - 1) - xb; \
    float mv = mvv[sl][i]; \
    w00[i] = (vy0 && vx0) ? (1.f - wy) * (1.f - wx) * mv : 0.f; \
    w01[i] = (vy0 && vx1) ? (1.f - wy) * wx * mv : 0.f; \
    w10[i] = (vy1 && vx0) ? wy * (1.f - wx) * mv : 0.f; \
    w11[i] = (vy1 && vx1) ? wy * wx * mv : 0.f; \
    const f16* xp = xpl + (size_t)i * ((size_t)HW * 8); \
    g0[i] = *(const f16x8*)&xp[(size_t)(y0c * Ww + xb) * 8]; \
    g1[i] = *(const f16x8*)&xp[(size_t)(y1c * Ww + xb) * 8]; } }

#define FIN(nb) { \
  f16 o[16]; \
  _Pragma("unroll") \
  for (int i = 0; i < 4; i++) { \
    _Pragma("unroll") \
    for (int c = 0; c < 4; c++) { \
      float a00 = (float)g0[i][c]; \
      float a01 = hsel[i] ? (float)g0[i][4 + c] : (float)g0[i][c]; \
      float a10 = (float)g1[i][c]; \
      float a11 = hsel[i] ? (float)g1[i][4 + c] : (float)g1[i][c]; \
      o[i * 4 + c] = (f16)(a00 * w00[i] + a01 * w01[i] + a10 * w10[i] + a11 * w11[i]); } } \
  *(uint4*)&buf[nb][pxl][dg2 * 16] = *(uint4*)&o[0]; \
  *(uint4*)&buf[nb][pxl][dg2 * 16 + 8] = *(uint4*)&o[8]; }

#define MFMA_TAP(kk) { \
  _Pragma("unroll") \
  for (int ch = 0; ch < 2; ch++) { \
    f16x8 bfr = *(const f16x8*)&buf[(kk) & 1][wave * 16 + (lane & 15)][(lane >> 4) * 8 + ch * 32]; \
    const f16* wc = wtd + ((size_t)(((kk) * 2 + ch) * 4) * 64 + (size_t)lane) * 8; \
    _Pragma("unroll") \
    for (int f = 0; f < 4; f++) { \
      f16x8 a = *(const f16x8*)&wc[(size_t)f * 512]; \
      acc[f] = __builtin_amdgcn_mfma_f32_16x16x32_f16(a, bfr, acc[f], 0, 0, 0); } } }

  OFF_LOAD(0, 0);
  GATHER(0, 0);
  OFF_LOAD(1, 1);
  FIN(0);
  __syncthreads();

  #pragma unroll
  for (int k = 0; k < 9; k++) {
    if (k < 8) { GATHER(k + 1, (k + 1) & 1); }
    if (k < 7) { OFF_LOAD(k + 2, k & 1); }
    MFMA_TAP(k);
    if (k < 8) { FIN((k + 1) & 1); }
    __syncthreads();
  }

  const int pxo = px0 + wave * 16 + (lane & 15);
  #pragma unroll
  for (int f = 0; f < 4; f++) {
    #pragma unroll
    for (int r = 0; r < 4; r++) {
      int co = f * 16 + (lane >> 4) * 4 + r;
      out[((size_t)b * 64 + co) * HW + pxo] = acc[f][r] + bias[co];
    }
  }
#undef OFF_LOAD
#undef GATHER
#undef FIN
#undef MFMA_TAP
}

// ---------------- launch ----------------
extern "C" void kernel_launch(void* const* d_in, const int* in_sizes, int n_in,
                              void* d_out, int out_size, void* d_ws, size_t ws_size,
                              hipStream_t stream) {
  const float* x    = (const float*)d_in[0];
  const float* cond = (const float*)d_in[1];
  const float* flow = (const float*)d_in[2];
  const float* w1 = (const float*)d_in[3];
  const float* b1 = (const float*)d_in[4];
  const float* w2 = (const float*)d_in[5];
  const float* b2 = (const float*)d_in[6];
  const float* w3 = (const float*)d_in[7];
  const float* b3 = (const float*)d_in[8];
  const float* w4 = (const float*)d_in[9];
  const float* b4 = (const float*)d_in[10];
  const float* wD = (const float*)d_in[11];
  const float* bD = (const float*)d_in[12];
  float* out = (float*)d_out;
  const int B = 2;

  char* ws = (char*)d_ws;
  f16* condp = (f16*)ws;                         // 10,816,000
  f16* hA = (f16*)(ws + 10816000);               //  4,326,400
  f16* hB = (f16*)(ws + 15142400);               //  4,326,400
  char* pw = ws + 19468800;
  f16*   offb = (f16*)pw;            pw += 18874368;  // [B][288][HW] f16
  f16*   mskb = (f16*)pw;            pw += 9437184;   // [B][144][HW] f16
  f16*   xt2  = (f16*)pw;            pw += 8388608;
  f16*   wt1  = (f16*)pw;            pw += 184320;
  f16*   wt2  = (f16*)pw;            pw += 73728;
  f16*   wt3  = (f16*)pw;            pw += 73728;
  f16*   wt4  = (f16*)pw;            pw += 497664;
  f16*   wtd  = (f16*)pw;            pw += 73728;

  // fused prep + fused weight transposes (2 launches)
  prep_all_k<<<dim3((594208 + 255) / 256), 256, 0, stream>>>(cond, x, condp, hA, hB, xt2);
  wtrans_all_k<<<dim3((882 * 64 + 255) / 256), 256, 0, stream>>>(
      w1, w2, w3, w4, wD, wt1, wt2, wt3, wt4, wtd);

  // convs (f16 MFMA, 16x8 tiles, NCSTG=2 staging, hoisted B-fragments)
  conv_f16_k<160, 5, 2, 1, 4, 0><<<dim3(8, 16, B * 4), 256, 0, stream>>>(
      condp, wt1, b1, hA, nullptr, nullptr, nullptr, 4);
  conv_f16_k<64, 2, 2, 1, 4, 0><<<dim3(8, 16, B * 4), 256, 0, stream>>>(
      hA, wt2, b2, hB, nullptr, nullptr, nullptr, 4);
  conv_f16_k<64, 2, 2, 1, 4, 0><<<dim3(8, 16, B * 4), 256, 0, stream>>>(
      hB, wt3, b3, hA, nullptr, nullptr, nullptr, 4);
  conv_f16_k<64, 2, 2, 1, 27, 2><<<dim3(8, 16, B * 27), 256, 0, stream>>>(
      hA, wt4, b4, nullptr, offb, mskb, flow, 27);

  // fused deformable conv: R8 structure, f16 offsets
  dcn_fused_k<<<dim3(512), 256, 0, stream>>>(xt2, offb, mskb, wtd, bD, out);
}